// Round 6
// baseline (340.916 us; speedup 1.0000x reference)
//
#include <hip/hip_runtime.h>

#define NB 262144
#define AA 10
#define DD 10
#define KK 32

typedef unsigned int uint32;
typedef _Float16 h2 __attribute__((ext_vector_type(2)));

// ---- f16 helpers ------------------------------------------------------------
#if defined(__has_builtin)
#if __has_builtin(__builtin_amdgcn_fdot2)
#define HAVE_FDOT2 1
#endif
#endif

#ifdef HAVE_FDOT2
static __device__ __forceinline__ float fdot2(h2 a, h2 b, float c) {
    return __builtin_amdgcn_fdot2(a, b, c, false);   // v_dot2_f32_f16
}
#else
static __device__ __forceinline__ float fdot2(h2 a, h2 b, float c) {
    return fmaf((float)a.x, (float)b.x, fmaf((float)a.y, (float)b.y, c));
}
#endif

// v_cvt_pkrtz_f16_f32 returns __fp16x2; bitcast to our h2 (_Float16x2)
static __device__ __forceinline__ h2 pkrtz(float lo, float hi) {
    auto r = __builtin_amdgcn_cvt_pkrtz(lo, hi);
    union { decltype(r) a; h2 h; } c; c.a = r; return c.h;
}
static __device__ __forceinline__ h2 u2h(uint32 u) {
    union { uint32 u; h2 h; } c; c.u = u; return c.h;
}
static __device__ __forceinline__ uint32 h2u(h2 h) {
    union { uint32 u; h2 h; } c; c.h = h; return c.u;
}

// ---- bf16 helpers -----------------------------------------------------------
static __device__ __forceinline__ float b2f(unsigned short h) {
    union { uint32 u; float f; } c; c.u = ((uint32)h) << 16; return c.f;
}
static __device__ __forceinline__ float bflo(uint32 w) {
    union { uint32 u; float f; } c; c.u = w << 16; return c.f;
}
static __device__ __forceinline__ float bfhi(uint32 w) {
    union { uint32 u; float f; } c; c.u = w & 0xffff0000u; return c.f;
}

// f32-vs-bf16 detection by exponent-field statistics (verified earlier rounds).
__device__ __forceinline__ int detect_f32(const unsigned short* p, int nshorts,
                                          unsigned expthr, int lane) {
    int bad = 0;
    if (lane < nshorts) {
        unsigned e = (p[lane] >> 7) & 0xFFu;
        bad = (e >= expthr);
    }
    return __any(bad);
}

// ---- prep: convert + pack weights as f16 pairs into workspace ---------------
// wf layout (dwords):
//   [0:50)     Mrow pairs:  Mr[d*5+j] = {M[d][2j],  M[d][2j+1]}   (item: mv)
//   [50:100)   Mcol pairs:  Mc[e*5+j] = {M[2j][e],  M[2j+1][e]}   (user: um)
//   [128+12k)  user row k:  Pu[k] pairs(5) | Pi[k] pairs(5) | pu[k] f32 | pad
//   [512+12k)  item row k:  Pi[k] pairs(5) | Pu[k] pairs(5) | pi[k] f32 | pad
__global__ __launch_bounds__(64) void prep_weights(
    const unsigned short* __restrict__ wM,
    const unsigned short* __restrict__ wPu,
    const unsigned short* __restrict__ wpu,
    const unsigned short* __restrict__ wPi,
    const unsigned short* __restrict__ wpi,
    uint32* __restrict__ wf)
{
    const int t = threadIdx.x;
    int f = 0;
    f |= detect_f32(wM,  64, 125, t) << 0;
    f |= detect_f32(wPu, 64, 125, t) << 1;
    f |= detect_f32(wpu, 32, 125, t) << 2;
    f |= detect_f32(wPi, 64, 125, t) << 3;
    f |= detect_f32(wpi, 32, 125, t) << 4;
    const float* fM  = (const float*)wM;
    const float* fPu = (const float*)wPu;
    const float* fpu = (const float*)wpu;
    const float* fPi = (const float*)wPi;
    const float* fpi = (const float*)wpi;

    // M row pairs [0:50) and col pairs [50:100)
    for (int i = t; i < 100; i += 64) {
        if (i < 50) {
            const int d = i / 5, j = i % 5;
            float a = (f & 1) ? fM[d * 10 + 2 * j]     : b2f(wM[d * 10 + 2 * j]);
            float c = (f & 1) ? fM[d * 10 + 2 * j + 1] : b2f(wM[d * 10 + 2 * j + 1]);
            wf[i] = h2u(pkrtz(a, c));
        } else {
            const int ii = i - 50, e = ii / 5, j = ii % 5;
            float a = (f & 1) ? fM[(2 * j) * 10 + e]     : b2f(wM[(2 * j) * 10 + e]);
            float c = (f & 1) ? fM[(2 * j + 1) * 10 + e] : b2f(wM[(2 * j + 1) * 10 + e]);
            wf[i] = h2u(pkrtz(a, c));
        }
    }
    // k rows (user at 128, item at 512)
    for (int n = t; n < KK * 12; n += 64) {
        const int k = n / 12, j = n % 12;
        uint32 vu = 0, vi = 0;
        if (j < 5) {
            float a0 = (f & 2) ? fPu[k * 10 + 2 * j]     : b2f(wPu[k * 10 + 2 * j]);
            float a1 = (f & 2) ? fPu[k * 10 + 2 * j + 1] : b2f(wPu[k * 10 + 2 * j + 1]);
            float b0 = (f & 8) ? fPi[k * 10 + 2 * j]     : b2f(wPi[k * 10 + 2 * j]);
            float b1 = (f & 8) ? fPi[k * 10 + 2 * j + 1] : b2f(wPi[k * 10 + 2 * j + 1]);
            vu = h2u(pkrtz(a0, a1));
            vi = h2u(pkrtz(b0, b1));
        } else if (j < 10) {
            const int jj = j - 5;
            float a0 = (f & 8) ? fPi[k * 10 + 2 * jj]     : b2f(wPi[k * 10 + 2 * jj]);
            float a1 = (f & 8) ? fPi[k * 10 + 2 * jj + 1] : b2f(wPi[k * 10 + 2 * jj + 1]);
            float b0 = (f & 2) ? fPu[k * 10 + 2 * jj]     : b2f(wPu[k * 10 + 2 * jj]);
            float b1 = (f & 2) ? fPu[k * 10 + 2 * jj + 1] : b2f(wPu[k * 10 + 2 * jj + 1]);
            vu = h2u(pkrtz(a0, a1));
            vi = h2u(pkrtz(b0, b1));
        } else if (j == 10) {
            float a = (f & 4)  ? fpu[k] : b2f(wpu[k]);
            float b = (f & 16) ? fpi[k] : b2f(wpi[k]);
            union { float f; uint32 u; } ca, cb; ca.f = a; cb.f = b;
            vu = ca.u; vi = cb.u;
        }
        wf[128 + n] = vu;
        wf[512 + n] = vi;
    }
}

// ---- bulk loader: one batch row (100 elems) -> 50 f16 pairs -----------------
// bf16 -> f16 conversion exact for this value range (f16 has more mantissa).
static __device__ __forceinline__ void load_rep_h(const unsigned short* __restrict__ p,
                                                  int isf32, long long b, h2 R[AA][5]) {
    if (!isf32) {
        const uint2* g = (const uint2*)(p + b * 100);
        #pragma unroll
        for (int j = 0; j < 25; j++) {
            uint2 w = g[j];
            int e = 2 * j;
            R[e / 5][e % 5]             = pkrtz(bflo(w.x), bfhi(w.x));
            R[(e + 1) / 5][(e + 1) % 5] = pkrtz(bflo(w.y), bfhi(w.y));
        }
    } else {
        const float4* g = (const float4*)((const float*)p + b * 100);
        #pragma unroll
        for (int j = 0; j < 25; j++) {
            float4 w = g[j];
            int e = 2 * j;
            R[e / 5][e % 5]             = pkrtz(w.x, w.y);
            R[(e + 1) / 5][(e + 1) % 5] = pkrtz(w.z, w.w);
        }
    }
}

// ---- main kernel -------------------------------------------------------------
// Branch-split: blocks [0,4096) = user branch, [4096,8192) = item branch.
// Both branches run the SAME code with uniform parameters:
//   R = resident tensor rows (user branch: V;  item branch: U)   50 VGPRs
//   S = streamed row i       (user: U[u];      item: V[v])        5 VGPRs
//   T = MB x S               (user: um=U[u]M;  item: mv=M V[v])
//   per resident row q: r = relu(T . R[q]);  A += r * R[q]   (A = W[u] / X[v])
//   k-loop: s = wk[0..4].S + wk[5..9].A;  acc += wk_f32 * relu(s)
// i-loop rolled (I-cache); scores via tiny LDS (runtime index, no scratch).
// Peak live ~90 regs -> 5 waves/SIMD, no AGPR copy churn, no spills.
__global__ __launch_bounds__(64, 5) void aie_main(
    const unsigned short* __restrict__ user_rep,
    const unsigned short* __restrict__ item_rep,
    const uint32* __restrict__ wf,
    float* __restrict__ out)
{
    __shared__ float sc[64 * 11];   // 2.8 KB score buffer
    const int t = threadIdx.x;
    const int isItem = (int)(blockIdx.x >> 12);
    const long long b = (long long)(blockIdx.x & 4095) * 64 + t;

    const unsigned short* bulk = isItem ? user_rep : item_rep;
    const unsigned short* strm = isItem ? item_rep : user_rep;
    const int moff = isItem ? 0 : 50;     // Mr for item, Mc for user
    const int koff = isItem ? 512 : 128;  // weight-row block

    const int fb = detect_f32(bulk, 64, 137, t);
    const int fs = detect_f32(strm, 64, 137, t);

    h2 R[AA][5];
    load_rep_h(bulk, fb, b, R);

    const float* wff = (const float*)wf;

    #pragma unroll 1
    for (int i = 0; i < AA; i++) {
        // ---- stream row i (5 dwords, 4B-aligned in bf16 case) ----
        h2 S[5];
        if (!fs) {
            const uint32* g = (const uint32*)(strm + b * 100 + (long long)i * 10);
            #pragma unroll
            for (int j = 0; j < 5; j++) { uint32 w = g[j]; S[j] = pkrtz(bflo(w), bfhi(w)); }
        } else {
            const float2* g = (const float2*)((const float*)strm + b * 100 + (long long)i * 10);
            #pragma unroll
            for (int j = 0; j < 5; j++) { float2 w = g[j]; S[j] = pkrtz(w.x, w.y); }
        }

        // ---- T = MB * S  (um for user, mv for item) ----
        h2 T[5];
        #pragma unroll
        for (int x = 0; x < 5; x++) {
            float t0 = 0.f, t1 = 0.f;
            #pragma unroll
            for (int j = 0; j < 5; j++) {
                t0 = fdot2(u2h(wf[moff + (2 * x) * 5 + j]),     S[j], t0);
                t1 = fdot2(u2h(wf[moff + (2 * x + 1) * 5 + j]), S[j], t1);
            }
            T[x] = pkrtz(t0, t1);
        }

        // ---- A = sum_q relu(T . R[q]) * R[q] ----
        h2 A[5];
        #pragma unroll
        for (int j = 0; j < 5; j++) A[j] = pkrtz(0.f, 0.f);
        #pragma unroll
        for (int q = 0; q < AA; q++) {
            float r = 0.f;
            #pragma unroll
            for (int j = 0; j < 5; j++) r = fdot2(T[j], R[q][j], r);
            r = fmaxf(r, 0.f);
            h2 rd = pkrtz(r, r);
            #pragma unroll
            for (int j = 0; j < 5; j++) A[j] += rd * R[q][j];
        }

        // ---- k-loop (weights via uniform s_load) ----
        float acc = 0.f;
        #pragma unroll 2
        for (int k = 0; k < KK; k++) {
            const int o = koff + 12 * k;
            float s = 0.f;
            #pragma unroll
            for (int j = 0; j < 5; j++) s = fdot2(u2h(wf[o + j]), S[j], s);
            #pragma unroll
            for (int j = 0; j < 5; j++) s = fdot2(u2h(wf[o + 5 + j]), A[j], s);
            acc += wff[o + 10] * fmaxf(s, 0.f);
        }
        sc[t * 11 + i] = acc;
    }

    // ---- softmax + direct stores ----
    {
        float v[AA];
        #pragma unroll
        for (int i = 0; i < AA; i++) v[i] = sc[t * 11 + i];
        float mx = v[0];
        #pragma unroll
        for (int i = 1; i < AA; i++) mx = fmaxf(mx, v[i]);
        float s = 0.f;
        #pragma unroll
        for (int i = 0; i < AA; i++) { v[i] = __expf(v[i] - mx); s += v[i]; }
        const float inv = 1.f / s;
        float* o0 = out + (size_t)isItem * ((size_t)NB * 10) + b * 10;
        #pragma unroll
        for (int j = 0; j < 5; j++)
            *(float2*)(o0 + 2 * j) = make_float2(v[2 * j] * inv, v[2 * j + 1] * inv);
    }
}

extern "C" void kernel_launch(void* const* d_in, const int* in_sizes, int n_in,
                              void* d_out, int out_size, void* d_ws, size_t ws_size,
                              hipStream_t stream) {
    const unsigned short* user_rep = (const unsigned short*)d_in[0];
    const unsigned short* item_rep = (const unsigned short*)d_in[1];
    uint32* wf = (uint32*)d_ws;

    hipLaunchKernelGGL(prep_weights, dim3(1), dim3(64), 0, stream,
                       (const unsigned short*)d_in[2], (const unsigned short*)d_in[3],
                       (const unsigned short*)d_in[4], (const unsigned short*)d_in[5],
                       (const unsigned short*)d_in[6], wf);

    hipLaunchKernelGGL(aie_main, dim3(2 * (NB / 64)), dim3(64), 0, stream,
                       user_rep, item_rep, wf, (float*)d_out);
}